// Round 11
// baseline (350.577 us; speedup 1.0000x reference)
//
#include <hip/hip_runtime.h>
#include <math.h>

#define Bb 8
#define Nn 128
#define Dd 512
#define Hh 8
#define KTOP 89

typedef short s16x8 __attribute__((ext_vector_type(8)));
typedef float f32x4 __attribute__((ext_vector_type(4)));

__device__ __forceinline__ unsigned short bf16r(float f) {
    unsigned int u = __float_as_uint(f);
    u += 0x7FFFu + ((u >> 16) & 1u);
    return (unsigned short)(u >> 16);
}
__device__ __forceinline__ float tanh_fast(float x) {
    x = fminf(fmaxf(x, -15.f), 15.f);
    float e = exp2f(x * 2.8853900817779268f);   // e^(2x)
    return (e - 1.f) / (e + 1.f);
}

// ---------------- generic GEMM: C[M][N] = A[M][K] @ W[N][K]^T (+bias) ----------------
__global__ __launch_bounds__(256)
void gemm_xwT(const float* __restrict__ A, const float* __restrict__ W,
              const float* __restrict__ bias, float* __restrict__ C,
              int M, int N, int K)
{
    __shared__ float As[16][64];
    __shared__ float Ws[16][64];
    const int tid = threadIdx.x;
    const int tx = tid & 15, ty = tid >> 4;
    const int m0 = blockIdx.x << 6, n0 = blockIdx.y << 6;
    const int lr = tid >> 2, lc = (tid & 3) << 2;
    float acc[4][4] = {};
    const float* Ap = A + (size_t)(m0 + lr) * K + lc;
    const float* Wp = W + (size_t)(n0 + lr) * K + lc;
    for (int k0 = 0; k0 < K; k0 += 16) {
        float4 a4 = *(const float4*)(Ap + k0);
        float4 w4 = *(const float4*)(Wp + k0);
        __syncthreads();
        As[lc+0][lr] = a4.x; As[lc+1][lr] = a4.y; As[lc+2][lr] = a4.z; As[lc+3][lr] = a4.w;
        Ws[lc+0][lr] = w4.x; Ws[lc+1][lr] = w4.y; Ws[lc+2][lr] = w4.z; Ws[lc+3][lr] = w4.w;
        __syncthreads();
#pragma unroll
        for (int kk = 0; kk < 16; ++kk) {
            float a[4], w[4];
            *(float4*)a = *(const float4*)&As[kk][tx << 2];
            *(float4*)w = *(const float4*)&Ws[kk][ty << 2];
#pragma unroll
            for (int i2 = 0; i2 < 4; ++i2)
#pragma unroll
                for (int j2 = 0; j2 < 4; ++j2)
                    acc[i2][j2] += a[i2] * w[j2];
        }
    }
#pragma unroll
    for (int i2 = 0; i2 < 4; ++i2) {
        const int m = m0 + (tx << 2) + i2;
#pragma unroll
        for (int j2 = 0; j2 < 4; ++j2) {
            const int n = n0 + (ty << 2) + j2;
            float v = acc[i2][j2];
            if (bias) v += bias[n];
            C[(size_t)m * N + n] = v;
        }
    }
}

// ---------------- pack MLP weights to bf16, [out][in] row-major ----------------
__global__ __launch_bounds__(256)
void prep2(const float* __restrict__ wep, const float* __restrict__ w1,
           const float* __restrict__ w2, const float* __restrict__ w3,
           unsigned short* __restrict__ wepb, unsigned short* __restrict__ w1b,
           float* __restrict__ w1last, unsigned short* __restrict__ w2b,
           unsigned short* __restrict__ w3b)
{
    const int t = blockIdx.x * 256 + threadIdx.x;
    if (t < 32768) {                       // wepb[128][256] <- w_ep[:, :256]
        const int o = t >> 8, k = t & 255;
        wepb[t] = bf16r(wep[(size_t)o * 512 + k]);
    }
    if (t < 98304) {                       // w1b[256][384] <- w1[:, :384]
        const int o = t / 384, k = t - o * 384;
        w1b[t] = bf16r(w1[(size_t)o * 385 + k]);
    }
    if (t < 256) w1last[t] = w1[(size_t)t * 385 + 384];
    if (t < 32768) w2b[t] = bf16r(w2[t]); // w2b[128][256]
    if (t < 2048) {                        // w3b[16][128], rows 8..15 zero
        const int o = t >> 7, k = t & 127;
        w3b[t] = (o < 8) ? bf16r(w3[o * 128 + k]) : (unsigned short)0;
    }
}

// ---------------- chemical distances via min-plus squaring ----------------
// clip(FW shortest path, 3.0) == clip(min over <=4-edge paths, 3.0):
// min edge weight 0.6  =>  any >=5-edge path >= 3.0 (clips to 3.0 either way).
__global__ __launch_bounds__(256)
void build_adj(const float* __restrict__ efeat, float* __restrict__ adj)
{
    const int e = blockIdx.x * 256 + threadIdx.x;   // 131072 total
    const int ii = (e >> 7) & 127, jj = e & 127;
    const float* p = efeat + (size_t)e * 5;
    float v0 = p[0], v1 = p[1], v2 = p[2], v3 = p[3], v4 = p[4];
    float best = v0; int bx = 0;
    if (v1 > best) { best = v1; bx = 1; }
    if (v2 > best) { best = v2; bx = 2; }
    if (v3 > best) { best = v3; bx = 3; }
    if (v4 > best) { best = v4; bx = 4; }
    float w = (bx == 1) ? 1.0f : (bx == 2) ? 0.8f : (bx == 3) ? 0.6f
            : (bx == 4) ? 0.9f : INFINITY;
    adj[e] = (ii == jj) ? 0.0f : w;
}

// block = (batch, 8-row tile): grid 8*16 = 128.  Full input matrix in LDS.
__global__ __launch_bounds__(256)
void minplus_square(const float* __restrict__ Din, float* __restrict__ Dout)
{
    __shared__ float Ds[128][132];
    const int tid = threadIdx.x;
    const int b = blockIdx.x >> 4;
    const int t = blockIdx.x & 15;
    const float* src = Din + (size_t)b * 16384;
    for (int e = tid; e < 16384; e += 256)
        Ds[e >> 7][e & 127] = src[e];
    __syncthreads();
    const int i  = (t << 3) + (tid >> 5);
    const int j0 = (tid & 31) << 2;
    float a0 = INFINITY, a1 = INFINITY, a2 = INFINITY, a3 = INFINITY;
#pragma unroll 4
    for (int k = 0; k < 128; ++k) {
        const float dik = Ds[i][k];
        float4 r = *(const float4*)&Ds[k][j0];
        a0 = fminf(a0, dik + r.x);
        a1 = fminf(a1, dik + r.y);
        a2 = fminf(a2, dik + r.z);
        a3 = fminf(a3, dik + r.w);
    }
    float4 o = {a0, a1, a2, a3};
    *(float4*)&Dout[(size_t)b * 16384 + i * 128 + j0] = o;
}

// ---------------- pair MLP via bf16 MFMA -> sp[B][H][N][N] ----------------
// block = (b, i, j-half): M = 64 pairs.  8 waves split N.
// T2-style XOR swizzle on all LDS tiles: byte ^= ((row&7)<<4).  Row strides are
// exact multiples of 128B so the XOR stays in-row; b128 reads land uniformly on
// all 8 bank-groups (block8 = lq ^ (lr&7)); b16 writebacks drop to ~2-way.
// Arithmetic is bit-identical to the previous (AS=392) version.
#define ASB 768   // A1 row stride bytes (384 bf16 = ef 256 | ep 128)
#define HSB 256   // Hs row stride bytes (128 bf16)

__global__ __launch_bounds__(512, 4)
void mlp2(const float* __restrict__ npf, const float* __restrict__ dist,
          const unsigned short* __restrict__ wepb, const float* __restrict__ bep,
          const unsigned short* __restrict__ w1b, const float* __restrict__ w1last,
          const float* __restrict__ b1,
          const unsigned short* __restrict__ w2b, const float* __restrict__ b2,
          const unsigned short* __restrict__ w3b, const float* __restrict__ b3,
          float* __restrict__ sp)
{
    const int bid = blockIdx.x;
    const int jh = bid & 1;
    const int i  = (bid >> 1) & 127;
    const int b  = bid >> 8;
    const int j0 = jh << 6;
    const int tid = threadIdx.x;
    const int w  = tid >> 6;        // wave 0..7
    const int l  = tid & 63;
    const int lr = l & 15;          // MFMA row/col lane index
    const int lq = l >> 4;          // MFMA k-quarter / row-group

    __shared__ unsigned short A1s[64 * 384];
    __shared__ unsigned short Hs[64 * 128];
    __shared__ float npis[256];
    __shared__ float cdl[64];
    char* A1c = (char*)A1s;
    char* Hc  = (char*)Hs;

    if (tid < 256) npis[tid] = npf[(size_t)(b * Nn + i) * 256 + tid];
    else if (tid < 320) {
        const int r = tid - 256;
        float dv = dist[((size_t)(b * Nn) + i) * Nn + j0 + r];
        cdl[r] = fminf(dv, 3.0f) * (1.0f / 3.0f);
    }
    __syncthreads();

    {   // ef = tanh(np_i + np_j) -> A1[:, 0:256] bf16 (swizzled b128 writes)
        const int row = tid & 63;
        const int sw  = (row & 7) << 4;
        const int c0  = (tid >> 6) * 32;
        const float* npj = npf + (size_t)(b * Nn + j0 + row) * 256 + c0;
#pragma unroll
        for (int c = 0; c < 32; c += 8) {
            float4 x0 = *(const float4*)(npj + c);
            float4 x1 = *(const float4*)(npj + c + 4);
            float v[8] = {x0.x, x0.y, x0.z, x0.w, x1.x, x1.y, x1.z, x1.w};
            unsigned int pk[4];
#pragma unroll
            for (int e = 0; e < 8; e += 2) {
                float t0 = tanh_fast(npis[c0 + c + e]     + v[e]);
                float t1 = tanh_fast(npis[c0 + c + e + 1] + v[e + 1]);
                pk[e >> 1] = ((unsigned int)bf16r(t1) << 16) | bf16r(t0);
            }
            *(uint4*)(A1c + row * ASB + (((c0 + c) * 2) ^ sw)) = *(uint4*)pk;
        }
    }
    __syncthreads();

    {   // ep = ef @ wep^T + bep  -> A1[:, 256:384].  wave owns cols [w*16, w*16+16)
        f32x4 acc[4] = {};
        for (int k0 = 0; k0 < 256; k0 += 32) {
            s16x8 bw = *(const s16x8*)&wepb[(size_t)(w * 16 + lr) * 256 + k0 + lq * 8];
#pragma unroll
            for (int mt = 0; mt < 4; ++mt) {
                const int row = mt * 16 + lr;
                s16x8 av = *(const s16x8*)(A1c + row * ASB +
                                           (((k0 + lq * 8) * 2) ^ ((row & 7) << 4)));
                acc[mt] = __builtin_amdgcn_mfma_f32_16x16x32_bf16(av, bw, acc[mt], 0, 0, 0);
            }
        }
        const float bb = bep[w * 16 + lr];
#pragma unroll
        for (int mt = 0; mt < 4; ++mt)
#pragma unroll
            for (int rg = 0; rg < 4; ++rg) {
                const int row = mt * 16 + lq * 4 + rg;
                *(unsigned short*)(A1c + row * ASB +
                    (((256 + w * 16 + lr) * 2) ^ ((row & 7) << 4))) = bf16r(acc[mt][rg] + bb);
            }
    }
    __syncthreads();

    // h1 (two 128-col passes) feeding h2 accumulation
    f32x4 acc2[4] = {};
    for (int p = 0; p < 2; ++p) {
        const int nc = p * 128 + w * 16;   // h1 col base for this wave
        f32x4 acc[4] = {};
        for (int k0 = 0; k0 < 384; k0 += 32) {
            s16x8 bw = *(const s16x8*)&w1b[(size_t)(nc + lr) * 384 + k0 + lq * 8];
#pragma unroll
            for (int mt = 0; mt < 4; ++mt) {
                const int row = mt * 16 + lr;
                s16x8 av = *(const s16x8*)(A1c + row * ASB +
                                           (((k0 + lq * 8) * 2) ^ ((row & 7) << 4)));
                acc[mt] = __builtin_amdgcn_mfma_f32_16x16x32_bf16(av, bw, acc[mt], 0, 0, 0);
            }
        }
        const float wl = w1last[nc + lr];
        const float bb = b1[nc + lr];
#pragma unroll
        for (int mt = 0; mt < 4; ++mt) {
            f32x4 cdv = *(const f32x4*)&cdl[mt * 16 + lq * 4];
#pragma unroll
            for (int rg = 0; rg < 4; ++rg) {
                const int row = mt * 16 + lq * 4 + rg;
                float hv = fmaxf(acc[mt][rg] + cdv[rg] * wl + bb, 0.f);
                *(unsigned short*)(Hc + row * HSB +
                    (((w * 16 + lr) * 2) ^ ((row & 7) << 4))) = bf16r(hv);
            }
        }
        __syncthreads();
        // h2 partial: K-slice [p*128, p*128+128), wave owns h2 cols [w*16, w*16+16)
        for (int k0 = 0; k0 < 128; k0 += 32) {
            s16x8 bw = *(const s16x8*)&w2b[(size_t)(w * 16 + lr) * 256 + p * 128 + k0 + lq * 8];
#pragma unroll
            for (int mt = 0; mt < 4; ++mt) {
                const int row = mt * 16 + lr;
                s16x8 av = *(const s16x8*)(Hc + row * HSB +
                                           (((k0 + lq * 8) * 2) ^ ((row & 7) << 4)));
                acc2[mt] = __builtin_amdgcn_mfma_f32_16x16x32_bf16(av, bw, acc2[mt], 0, 0, 0);
            }
        }
        __syncthreads();   // before next pass overwrites Hs
    }

    {   // h2 = relu(acc2 + b2) -> Hs (reuse) bf16
        const float bb = b2[w * 16 + lr];
#pragma unroll
        for (int mt = 0; mt < 4; ++mt)
#pragma unroll
            for (int rg = 0; rg < 4; ++rg) {
                const int row = mt * 16 + lq * 4 + rg;
                *(unsigned short*)(Hc + row * HSB +
                    (((w * 16 + lr) * 2) ^ ((row & 7) << 4))) =
                    bf16r(fmaxf(acc2[mt][rg] + bb, 0.f));
            }
    }
    __syncthreads();

    // logits = h2 @ w3^T + b3 -> sigmoid -> sp.  waves 0..3 each take one M-tile.
    if (w < 4) {
        f32x4 acc3 = {};
        for (int k0 = 0; k0 < 128; k0 += 32) {
            s16x8 bw = *(const s16x8*)&w3b[lr * 128 + k0 + lq * 8];
            const int row = w * 16 + lr;
            s16x8 av = *(const s16x8*)(Hc + row * HSB +
                                       (((k0 + lq * 8) * 2) ^ ((row & 7) << 4)));
            acc3 = __builtin_amdgcn_mfma_f32_16x16x32_bf16(av, bw, acc3, 0, 0, 0);
        }
        if (lr < 8) {   // col = head
            const float bb = b3[lr];
            const int jbase = j0 + w * 16 + lq * 4;
            float pv[4];
#pragma unroll
            for (int rg = 0; rg < 4; ++rg) {
                float lg = acc3[rg] + bb;
                float s  = 1.0f / (1.0f + exp2f(-lg * 1.4426950408889634f));
                pv[rg] = (jbase + rg == i) ? 1.0f : s;
            }
            *(float4*)&sp[(((size_t)(b * Hh + lr)) * Nn + i) * Nn + jbase] = *(float4*)pv;
        }
    }
}

// ---------------- attention: scores * sp, exact top-89, sparse softmax, A@V ----------------
__global__ __launch_bounds__(256)
void attn_kernel(const float* __restrict__ qkv, const float* __restrict__ sp,
                 float* __restrict__ aout)
{
    const int blk = blockIdx.x;
    const int qt = blk & 15;
    const int h  = (blk >> 4) & 7;
    const int b  = blk >> 7;
    const int tid = threadIdx.x;
    const int w = tid >> 6, lane = tid & 63;

    __shared__ float kT[64][132];
    __shared__ float sw[4][128];
    __shared__ float qs[4][64];

    {
        const int j = tid >> 1, d0 = (tid & 1) << 5;
        const float* kp = qkv + (size_t)(b * Nn + j) * 1536 + 512 + h * 64 + d0;
#pragma unroll
        for (int c = 0; c < 32; c += 4) {
            float4 kv = *(const float4*)(kp + c);
            kT[d0+c+0][j] = kv.x;
            kT[d0+c+1][j] = kv.y;
            kT[d0+c+2][j] = kv.z;
            kT[d0+c+3][j] = kv.w;
        }
    }
    __syncthreads();

    const float* vbase = qkv + (size_t)(b * Nn) * 1536 + 1024 + h * 64 + lane;

    for (int r = 0; r < 2; ++r) {
        const int q = (qt << 3) + (w << 1) + r;
        qs[w][lane] = qkv[(size_t)(b * Nn + q) * 1536 + h * 64 + lane];
        float acc1 = 0.f, acc2 = 0.f;
#pragma unroll
        for (int d = 0; d < 64; d += 4) {
            float qv[4];
            *(float4*)qv = *(const float4*)&qs[w][d];
            acc1 += qv[0]*kT[d+0][lane]    + qv[1]*kT[d+1][lane]
                  + qv[2]*kT[d+2][lane]    + qv[3]*kT[d+3][lane];
            acc2 += qv[0]*kT[d+0][lane+64] + qv[1]*kT[d+1][lane+64]
                  + qv[2]*kT[d+2][lane+64] + qv[3]*kT[d+3][lane+64];
        }
        const float* sprow = sp + (((size_t)(b * Hh + h)) * Nn + q) * Nn;
        const float m1 = acc1 * 0.125f * sprow[lane];
        const float m2 = acc2 * 0.125f * sprow[lane + 64];
        sw[w][lane]      = m1;
        sw[w][lane + 64] = m2;
        int r1 = 0, r2 = 0;
        for (int jj = 0; jj < 128; ++jj) {
            const float mv = sw[w][jj];
            r1 += (mv > m1 || (mv == m1 && jj < lane)) ? 1 : 0;
            r2 += (mv > m2 || (mv == m2 && jj < lane + 64)) ? 1 : 0;
        }
        float gm = fmaxf(m1, m2);
#pragma unroll
        for (int off = 32; off > 0; off >>= 1) gm = fmaxf(gm, __shfl_xor(gm, off, 64));
        const float M = fmaxf(gm, 0.0f);
        const float e1 = expf((r1 < KTOP ? m1 : 0.0f) - M);
        const float e2 = expf((r2 < KTOP ? m2 : 0.0f) - M);
        float dsum = e1 + e2;
#pragma unroll
        for (int off = 32; off > 0; off >>= 1) dsum += __shfl_xor(dsum, off, 64);
        const float inv = 1.0f / dsum;
        sw[w][lane]      = e1 * inv;
        sw[w][lane + 64] = e2 * inv;
        float acc = 0.f;
        for (int jj = 0; jj < 128; ++jj)
            acc += sw[w][jj] * vbase[(size_t)jj * 1536];
        aout[(size_t)(b * Nn + q) * Dd + h * 64 + lane] = acc;
    }
}

extern "C" void kernel_launch(void* const* d_in, const int* in_sizes, int n_in,
                              void* d_out, int out_size, void* d_ws, size_t ws_size,
                              hipStream_t stream)
{
    const float* x      = (const float*)d_in[0];
    const float* efeat  = (const float*)d_in[2];
    const float* w_qkv  = (const float*)d_in[3];
    const float* w_proj = (const float*)d_in[4];
    const float* b_proj = (const float*)d_in[5];
    const float* w_np   = (const float*)d_in[6];
    const float* b_np   = (const float*)d_in[7];
    const float* w_ep   = (const float*)d_in[8];
    const float* b_ep   = (const float*)d_in[9];
    const float* w1     = (const float*)d_in[10];
    const float* b1     = (const float*)d_in[11];
    const float* w2     = (const float*)d_in[12];
    const float* b2     = (const float*)d_in[13];
    const float* w3     = (const float*)d_in[14];
    const float* b3     = (const float*)d_in[15];
    float* out = (float*)d_out;

    float* ws     = (float*)d_ws;
    float* qkv    = ws;                    // 1,572,864 f32
    float* npb    = qkv    + 1572864;      //   262,144
    float* dist   = npb    + 262144;       //   131,072
    float* spb    = dist   + 131072;       // 1,048,576
    float* aout   = spb    + 1048576;      //   524,288
    float* w1last = aout   + 524288;       //       256
    unsigned short* wepb = (unsigned short*)(w1last + 256);  // 32768
    unsigned short* w1b  = wepb + 32768;                     // 98304
    unsigned short* w2b  = w1b  + 98304;                     // 32768
    unsigned short* w3b  = w2b  + 32768;                     //  2048
    float* dtmp   = (float*)(w3b + 2048);  //   131,072 f32

    prep2<<<384, 256, 0, stream>>>(w_ep, w1, w2, w3, wepb, w1b, w1last, w2b, w3b);
    gemm_xwT<<<dim3(16, 24), 256, 0, stream>>>(x, w_qkv, nullptr, qkv, 1024, 1536, 512);
    gemm_xwT<<<dim3(16, 4),  256, 0, stream>>>(x, w_np, b_np, npb, 1024, 256, 512);
    build_adj<<<512, 256, 0, stream>>>(efeat, dist);
    minplus_square<<<128, 256, 0, stream>>>(dist, dtmp);   // <=2-edge paths
    minplus_square<<<128, 256, 0, stream>>>(dtmp, dist);   // <=4-edge paths
    mlp2<<<2048, 512, 0, stream>>>(npb, dist, wepb, b_ep, w1b, w1last, b1,
                                   w2b, b2, w3b, b3, spb);
    attn_kernel<<<1024, 256, 0, stream>>>(qkv, spb, aout);
    gemm_xwT<<<dim3(16, 8),  256, 0, stream>>>(aout, w_proj, b_proj, out, 1024, 512, 512);
}

// Round 12
// 328.076 us; speedup vs baseline: 1.0686x; 1.0686x over previous
//
#include <hip/hip_runtime.h>
#include <math.h>

#define Bb 8
#define Nn 128
#define Dd 512
#define Hh 8
#define KTOP 89

typedef short s16x8 __attribute__((ext_vector_type(8)));
typedef float f32x4 __attribute__((ext_vector_type(4)));

__device__ __forceinline__ unsigned short bf16r(float f) {
    unsigned int u = __float_as_uint(f);
    u += 0x7FFFu + ((u >> 16) & 1u);
    return (unsigned short)(u >> 16);
}
__device__ __forceinline__ float tanh_fast(float x) {
    x = fminf(fmaxf(x, -15.f), 15.f);
    float e = exp2f(x * 2.8853900817779268f);   // e^(2x)
    return (e - 1.f) / (e + 1.f);
}

// ---------------- generic GEMM: C[M][N] = A[M][K] @ W[N][K]^T (+bias) ----------------
__global__ __launch_bounds__(256)
void gemm_xwT(const float* __restrict__ A, const float* __restrict__ W,
              const float* __restrict__ bias, float* __restrict__ C,
              int M, int N, int K)
{
    __shared__ float As[16][64];
    __shared__ float Ws[16][64];
    const int tid = threadIdx.x;
    const int tx = tid & 15, ty = tid >> 4;
    const int m0 = blockIdx.x << 6, n0 = blockIdx.y << 6;
    const int lr = tid >> 2, lc = (tid & 3) << 2;
    float acc[4][4] = {};
    const float* Ap = A + (size_t)(m0 + lr) * K + lc;
    const float* Wp = W + (size_t)(n0 + lr) * K + lc;
    for (int k0 = 0; k0 < K; k0 += 16) {
        float4 a4 = *(const float4*)(Ap + k0);
        float4 w4 = *(const float4*)(Wp + k0);
        __syncthreads();
        As[lc+0][lr] = a4.x; As[lc+1][lr] = a4.y; As[lc+2][lr] = a4.z; As[lc+3][lr] = a4.w;
        Ws[lc+0][lr] = w4.x; Ws[lc+1][lr] = w4.y; Ws[lc+2][lr] = w4.z; Ws[lc+3][lr] = w4.w;
        __syncthreads();
#pragma unroll
        for (int kk = 0; kk < 16; ++kk) {
            float a[4], w[4];
            *(float4*)a = *(const float4*)&As[kk][tx << 2];
            *(float4*)w = *(const float4*)&Ws[kk][ty << 2];
#pragma unroll
            for (int i2 = 0; i2 < 4; ++i2)
#pragma unroll
                for (int j2 = 0; j2 < 4; ++j2)
                    acc[i2][j2] += a[i2] * w[j2];
        }
    }
#pragma unroll
    for (int i2 = 0; i2 < 4; ++i2) {
        const int m = m0 + (tx << 2) + i2;
#pragma unroll
        for (int j2 = 0; j2 < 4; ++j2) {
            const int n = n0 + (ty << 2) + j2;
            float v = acc[i2][j2];
            if (bias) v += bias[n];
            C[(size_t)m * N + n] = v;
        }
    }
}

// ---------------- fold ep layer into h1 weights ----------------
// h1 = relu(ef@W1a^T + ep@W1b^T + cd*w1last + b1), ep = ef@wep^T + bep  (all linear)
// => Afold[n][k] = w1[n][k] + sum_m wep[m][k]*w1[n][256+m];  bc[n] = b1[n] + sum_m bep[m]*w1[n][256+m]
__global__ __launch_bounds__(256)
void prep_fold(const float* __restrict__ w1, const float* __restrict__ wep,
               const float* __restrict__ b1, const float* __restrict__ bep,
               unsigned short* __restrict__ Afold, float* __restrict__ bc)
{
    const int n = blockIdx.x, k = threadIdx.x;
    const float* w1e = w1 + (size_t)n * 385 + 256;
    float acc = w1[(size_t)n * 385 + k];
#pragma unroll 4
    for (int m = 0; m < 128; ++m)
        acc += wep[(size_t)m * 512 + k] * w1e[m];
    Afold[(size_t)n * 256 + k] = bf16r(acc);
    if (k == 0) {
        float bacc = b1[n];
        for (int m = 0; m < 128; ++m) bacc += bep[m] * w1e[m];
        bc[n] = bacc;
    }
}

// ---------------- pack remaining MLP weights to bf16 ----------------
__global__ __launch_bounds__(256)
void prep2(const float* __restrict__ w1, const float* __restrict__ w2,
           const float* __restrict__ w3,
           float* __restrict__ w1last, unsigned short* __restrict__ w2b,
           unsigned short* __restrict__ w3b)
{
    const int t = blockIdx.x * 256 + threadIdx.x;
    if (t < 32768) w2b[t] = bf16r(w2[t]);        // w2b[128][256]
    if (t < 256) w1last[t] = w1[(size_t)t * 385 + 384];
    if (t < 2048) {                               // w3b[16][128], rows 8..15 zero
        const int o = t >> 7, k = t & 127;
        w3b[t] = (o < 8) ? bf16r(w3[o * 128 + k]) : (unsigned short)0;
    }
}

// ---------------- chemical distances via min-plus squaring ----------------
// clip(FW shortest path, 3.0) == clip(min over <=4-edge paths, 3.0):
// min edge weight 0.6  =>  any >=5-edge path >= 3.0 (clips to 3.0 either way).
__global__ __launch_bounds__(256)
void build_adj(const float* __restrict__ efeat, float* __restrict__ adj)
{
    const int e = blockIdx.x * 256 + threadIdx.x;   // 131072 total
    const int ii = (e >> 7) & 127, jj = e & 127;
    const float* p = efeat + (size_t)e * 5;
    float v0 = p[0], v1 = p[1], v2 = p[2], v3 = p[3], v4 = p[4];
    float best = v0; int bx = 0;
    if (v1 > best) { best = v1; bx = 1; }
    if (v2 > best) { best = v2; bx = 2; }
    if (v3 > best) { best = v3; bx = 3; }
    if (v4 > best) { best = v4; bx = 4; }
    float w = (bx == 1) ? 1.0f : (bx == 2) ? 0.8f : (bx == 3) ? 0.6f
            : (bx == 4) ? 0.9f : INFINITY;
    adj[e] = (ii == jj) ? 0.0f : w;
}

// block = (batch, 8-row tile): grid 8*16 = 128.  Full input matrix in LDS.
__global__ __launch_bounds__(256)
void minplus_square(const float* __restrict__ Din, float* __restrict__ Dout)
{
    __shared__ float Ds[128][132];
    const int tid = threadIdx.x;
    const int b = blockIdx.x >> 4;
    const int t = blockIdx.x & 15;
    const float* src = Din + (size_t)b * 16384;
    for (int e = tid; e < 16384; e += 256)
        Ds[e >> 7][e & 127] = src[e];
    __syncthreads();
    const int i  = (t << 3) + (tid >> 5);
    const int j0 = (tid & 31) << 2;
    float a0 = INFINITY, a1 = INFINITY, a2 = INFINITY, a3 = INFINITY;
#pragma unroll 4
    for (int k = 0; k < 128; ++k) {
        const float dik = Ds[i][k];
        float4 r = *(const float4*)&Ds[k][j0];
        a0 = fminf(a0, dik + r.x);
        a1 = fminf(a1, dik + r.y);
        a2 = fminf(a2, dik + r.z);
        a3 = fminf(a3, dik + r.w);
    }
    float4 o = {a0, a1, a2, a3};
    *(float4*)&Dout[(size_t)b * 16384 + i * 128 + j0] = o;
}

// ---------------- pair MLP via bf16 MFMA (ep folded) -> sp[B][H][N][N] ----------------
// block = (b, i, j-half): M = 64 pairs.  8 waves split N.  LDS ~51KB -> 3 blocks/CU.
// Odd 16B-granule strides ((stride/16)%8==1) keep b128 reads near-uniform (round-5
// addressing; round-11 showed the XOR swizzle was neutral and conflicts are benign 2-way).
#define AS2 264   // A1 row stride (256 ef cols + pad), 528B = 33*16
#define HS2 136   // Hs row stride, 272B = 17*16

__global__ __launch_bounds__(512, 6)
void mlp3(const float* __restrict__ npf, const float* __restrict__ dist,
          const unsigned short* __restrict__ Afold, const float* __restrict__ bc,
          const float* __restrict__ w1last,
          const unsigned short* __restrict__ w2b, const float* __restrict__ b2,
          const unsigned short* __restrict__ w3b, const float* __restrict__ b3,
          float* __restrict__ sp)
{
    const int bid = blockIdx.x;
    const int jh = bid & 1;
    const int i  = (bid >> 1) & 127;
    const int b  = bid >> 8;
    const int j0 = jh << 6;
    const int tid = threadIdx.x;
    const int w  = tid >> 6;        // wave 0..7
    const int l  = tid & 63;
    const int lr = l & 15;          // MFMA row/col lane index
    const int lq = l >> 4;          // MFMA k-quarter / row-group

    __shared__ unsigned short A1s[64 * AS2];   // 33792 B
    __shared__ unsigned short Hs[64 * HS2];    // 17408 B
    __shared__ float npis[256];
    __shared__ float cdl[64];

    if (tid < 256) npis[tid] = npf[(size_t)(b * Nn + i) * 256 + tid];
    else if (tid < 320) {
        const int r = tid - 256;
        float dv = dist[((size_t)(b * Nn) + i) * Nn + j0 + r];
        cdl[r] = fminf(dv, 3.0f) * (1.0f / 3.0f);
    }
    __syncthreads();

    {   // ef = tanh(np_i + np_j) -> A1 [64][256] bf16
        const int row = tid & 63;
        const int c0  = (tid >> 6) * 32;
        const float* npj = npf + (size_t)(b * Nn + j0 + row) * 256 + c0;
#pragma unroll
        for (int c = 0; c < 32; c += 8) {
            float4 x0 = *(const float4*)(npj + c);
            float4 x1 = *(const float4*)(npj + c + 4);
            float v[8] = {x0.x, x0.y, x0.z, x0.w, x1.x, x1.y, x1.z, x1.w};
            unsigned int pk[4];
#pragma unroll
            for (int e = 0; e < 8; e += 2) {
                float t0 = tanh_fast(npis[c0 + c + e]     + v[e]);
                float t1 = tanh_fast(npis[c0 + c + e + 1] + v[e + 1]);
                pk[e >> 1] = ((unsigned int)bf16r(t1) << 16) | bf16r(t0);
            }
            *(uint4*)&A1s[row * AS2 + c0 + c] = *(uint4*)pk;
        }
    }
    __syncthreads();

    // h1 (two 128-col passes over Afold) feeding h2 accumulation
    f32x4 acc2[4] = {};
    for (int p = 0; p < 2; ++p) {
        const int nc = p * 128 + w * 16;   // h1 col base for this wave
        f32x4 acc[4] = {};
        for (int k0 = 0; k0 < 256; k0 += 32) {
            s16x8 bw = *(const s16x8*)&Afold[(size_t)(nc + lr) * 256 + k0 + lq * 8];
#pragma unroll
            for (int mt = 0; mt < 4; ++mt) {
                s16x8 av = *(const s16x8*)&A1s[(mt * 16 + lr) * AS2 + k0 + lq * 8];
                acc[mt] = __builtin_amdgcn_mfma_f32_16x16x32_bf16(av, bw, acc[mt], 0, 0, 0);
            }
        }
        const float wl = w1last[nc + lr];
        const float bb = bc[nc + lr];
#pragma unroll
        for (int mt = 0; mt < 4; ++mt) {
            f32x4 cdv = *(const f32x4*)&cdl[mt * 16 + lq * 4];
#pragma unroll
            for (int rg = 0; rg < 4; ++rg) {
                float hv = fmaxf(acc[mt][rg] + cdv[rg] * wl + bb, 0.f);
                Hs[(mt * 16 + lq * 4 + rg) * HS2 + w * 16 + lr] = bf16r(hv);
            }
        }
        __syncthreads();
        // h2 partial: K-slice [p*128, p*128+128), wave owns h2 cols [w*16, w*16+16)
        for (int k0 = 0; k0 < 128; k0 += 32) {
            s16x8 bw = *(const s16x8*)&w2b[(size_t)(w * 16 + lr) * 256 + p * 128 + k0 + lq * 8];
#pragma unroll
            for (int mt = 0; mt < 4; ++mt) {
                s16x8 av = *(const s16x8*)&Hs[(mt * 16 + lr) * HS2 + k0 + lq * 8];
                acc2[mt] = __builtin_amdgcn_mfma_f32_16x16x32_bf16(av, bw, acc2[mt], 0, 0, 0);
            }
        }
        __syncthreads();   // before next pass overwrites Hs
    }

    {   // h2 = relu(acc2 + b2) -> Hs (reuse) bf16
        const float bb = b2[w * 16 + lr];
#pragma unroll
        for (int mt = 0; mt < 4; ++mt)
#pragma unroll
            for (int rg = 0; rg < 4; ++rg)
                Hs[(mt * 16 + lq * 4 + rg) * HS2 + w * 16 + lr] =
                    bf16r(fmaxf(acc2[mt][rg] + bb, 0.f));
    }
    __syncthreads();

    // logits = h2 @ w3^T + b3 -> sigmoid -> sp.  waves 0..3 each take one M-tile.
    if (w < 4) {
        f32x4 acc3 = {};
        for (int k0 = 0; k0 < 128; k0 += 32) {
            s16x8 bw = *(const s16x8*)&w3b[lr * 128 + k0 + lq * 8];
            s16x8 av = *(const s16x8*)&Hs[(w * 16 + lr) * HS2 + k0 + lq * 8];
            acc3 = __builtin_amdgcn_mfma_f32_16x16x32_bf16(av, bw, acc3, 0, 0, 0);
        }
        if (lr < 8) {   // col = head
            const float bb = b3[lr];
            const int jbase = j0 + w * 16 + lq * 4;
            float pv[4];
#pragma unroll
            for (int rg = 0; rg < 4; ++rg) {
                float lg = acc3[rg] + bb;
                float s  = 1.0f / (1.0f + exp2f(-lg * 1.4426950408889634f));
                pv[rg] = (jbase + rg == i) ? 1.0f : s;
            }
            *(float4*)&sp[(((size_t)(b * Hh + lr)) * Nn + i) * Nn + jbase] = *(float4*)pv;
        }
    }
}

// ---------------- attention: scores * sp, exact top-89, sparse softmax, A@V ----------------
__global__ __launch_bounds__(256)
void attn_kernel(const float* __restrict__ qkv, const float* __restrict__ sp,
                 float* __restrict__ aout)
{
    const int blk = blockIdx.x;
    const int qt = blk & 15;
    const int h  = (blk >> 4) & 7;
    const int b  = blk >> 7;
    const int tid = threadIdx.x;
    const int w = tid >> 6, lane = tid & 63;

    __shared__ float kT[64][132];
    __shared__ float sw[4][128];
    __shared__ float qs[4][64];

    {
        const int j = tid >> 1, d0 = (tid & 1) << 5;
        const float* kp = qkv + (size_t)(b * Nn + j) * 1536 + 512 + h * 64 + d0;
#pragma unroll
        for (int c = 0; c < 32; c += 4) {
            float4 kv = *(const float4*)(kp + c);
            kT[d0+c+0][j] = kv.x;
            kT[d0+c+1][j] = kv.y;
            kT[d0+c+2][j] = kv.z;
            kT[d0+c+3][j] = kv.w;
        }
    }
    __syncthreads();

    const float* vbase = qkv + (size_t)(b * Nn) * 1536 + 1024 + h * 64 + lane;

    for (int r = 0; r < 2; ++r) {
        const int q = (qt << 3) + (w << 1) + r;
        qs[w][lane] = qkv[(size_t)(b * Nn + q) * 1536 + h * 64 + lane];
        float acc1 = 0.f, acc2 = 0.f;
#pragma unroll
        for (int d = 0; d < 64; d += 4) {
            float qv[4];
            *(float4*)qv = *(const float4*)&qs[w][d];
            acc1 += qv[0]*kT[d+0][lane]    + qv[1]*kT[d+1][lane]
                  + qv[2]*kT[d+2][lane]    + qv[3]*kT[d+3][lane];
            acc2 += qv[0]*kT[d+0][lane+64] + qv[1]*kT[d+1][lane+64]
                  + qv[2]*kT[d+2][lane+64] + qv[3]*kT[d+3][lane+64];
        }
        const float* sprow = sp + (((size_t)(b * Hh + h)) * Nn + q) * Nn;
        const float m1 = acc1 * 0.125f * sprow[lane];
        const float m2 = acc2 * 0.125f * sprow[lane + 64];
        sw[w][lane]      = m1;
        sw[w][lane + 64] = m2;
        int r1 = 0, r2 = 0;
        for (int jj = 0; jj < 128; ++jj) {
            const float mv = sw[w][jj];
            r1 += (mv > m1 || (mv == m1 && jj < lane)) ? 1 : 0;
            r2 += (mv > m2 || (mv == m2 && jj < lane + 64)) ? 1 : 0;
        }
        float gm = fmaxf(m1, m2);
#pragma unroll
        for (int off = 32; off > 0; off >>= 1) gm = fmaxf(gm, __shfl_xor(gm, off, 64));
        const float M = fmaxf(gm, 0.0f);
        const float e1 = expf((r1 < KTOP ? m1 : 0.0f) - M);
        const float e2 = expf((r2 < KTOP ? m2 : 0.0f) - M);
        float dsum = e1 + e2;
#pragma unroll
        for (int off = 32; off > 0; off >>= 1) dsum += __shfl_xor(dsum, off, 64);
        const float inv = 1.0f / dsum;
        sw[w][lane]      = e1 * inv;
        sw[w][lane + 64] = e2 * inv;
        float acc = 0.f;
        for (int jj = 0; jj < 128; ++jj)
            acc += sw[w][jj] * vbase[(size_t)jj * 1536];
        aout[(size_t)(b * Nn + q) * Dd + h * 64 + lane] = acc;
    }
}

extern "C" void kernel_launch(void* const* d_in, const int* in_sizes, int n_in,
                              void* d_out, int out_size, void* d_ws, size_t ws_size,
                              hipStream_t stream)
{
    const float* x      = (const float*)d_in[0];
    const float* efeat  = (const float*)d_in[2];
    const float* w_qkv  = (const float*)d_in[3];
    const float* w_proj = (const float*)d_in[4];
    const float* b_proj = (const float*)d_in[5];
    const float* w_np   = (const float*)d_in[6];
    const float* b_np   = (const float*)d_in[7];
    const float* w_ep   = (const float*)d_in[8];
    const float* b_ep   = (const float*)d_in[9];
    const float* w1     = (const float*)d_in[10];
    const float* b1     = (const float*)d_in[11];
    const float* w2     = (const float*)d_in[12];
    const float* b2     = (const float*)d_in[13];
    const float* w3     = (const float*)d_in[14];
    const float* b3     = (const float*)d_in[15];
    float* out = (float*)d_out;

    float* ws     = (float*)d_ws;
    float* qkv    = ws;                    // 1,572,864 f32
    float* npb    = qkv    + 1572864;      //   262,144
    float* dist   = npb    + 262144;       //   131,072
    float* spb    = dist   + 131072;       // 1,048,576
    float* aout   = spb    + 1048576;      //   524,288
    float* w1last = aout   + 524288;       //       256
    float* bc     = w1last + 256;          //       256
    unsigned short* Afold = (unsigned short*)(bc + 256);     // 65536
    unsigned short* w2b   = Afold + 65536;                   // 32768
    unsigned short* w3b   = w2b   + 32768;                   //  2048
    float* dtmp   = (float*)(w3b + 2048);  //   131,072 f32

    prep_fold<<<256, 256, 0, stream>>>(w1, w_ep, b1, b_ep, Afold, bc);
    prep2<<<128, 256, 0, stream>>>(w1, w2, w3, w1last, w2b, w3b);
    gemm_xwT<<<dim3(16, 24), 256, 0, stream>>>(x, w_qkv, nullptr, qkv, 1024, 1536, 512);
    gemm_xwT<<<dim3(16, 4),  256, 0, stream>>>(x, w_np, b_np, npb, 1024, 256, 512);
    build_adj<<<512, 256, 0, stream>>>(efeat, dist);
    minplus_square<<<128, 256, 0, stream>>>(dist, dtmp);   // <=2-edge paths
    minplus_square<<<128, 256, 0, stream>>>(dtmp, dist);   // <=4-edge paths
    mlp3<<<2048, 512, 0, stream>>>(npb, dist, Afold, bc, w1last, w2b, b2, w3b, b3, spb);
    attn_kernel<<<1024, 256, 0, stream>>>(qkv, spb, aout);
    gemm_xwT<<<dim3(16, 8),  256, 0, stream>>>(aout, w_proj, b_proj, out, 1024, 512, 512);
}